// Round 3
// baseline (242.388 us; speedup 1.0000x reference)
//
#include <hip/hip_runtime.h>
#include <hip/hip_bf16.h>
#include <hip/hip_fp16.h>
#include <math.h>

#define B_ 8
#define N_ 2048
#define F_ 128

typedef __attribute__((ext_vector_type(8))) _Float16 half8;
typedef __attribute__((ext_vector_type(4))) float f32x4;

// ---------------------------------------------------------------------------
// Kernel 1: Wh = h @ W^T (fp32 compute), output:
//   - WhH: fp16, swizzled into MFMA B-fragment order:
//       element (b, j, o) at ((b*64 + j/32)*128 + o)*32 + ((j/8)%4)*8 + (j%8)
//   - sv = h . (W^T a_src), tv = h . (W^T a_dst)  (exact fp32)
// grid 512 = 256 row-blocks x 2 o-halves; 256 threads; 64 rows x 64 o per blk
// ---------------------------------------------------------------------------
__global__ __launch_bounds__(256) void k_wh(
    const float* __restrict__ h, const float* __restrict__ W,
    const float* __restrict__ a,
    _Float16* __restrict__ WhH, float* __restrict__ sv, float* __restrict__ tv)
{
    __shared__ float h_s[64][129];
    __shared__ float Wt[128][68];
    __shared__ float wsm[128], wtm[128];
    __shared__ float sred[64][4], tred[64][4];

    const int t = threadIdx.x;
    const int rowblk = blockIdx.x >> 1;
    const int ohalf  = blockIdx.x & 1;
    const int r0 = rowblk * 64;

    {
        const int f = (t & 31) * 4;
        #pragma unroll
        for (int it = 0; it < 8; ++it) {
            const int r = (t >> 5) + it * 8;
            float4 v = *(const float4*)&h[(size_t)(r0 + r) * F_ + f];
            h_s[r][f] = v.x; h_s[r][f + 1] = v.y;
            h_s[r][f + 2] = v.z; h_s[r][f + 3] = v.w;
        }
    }
    {
        const int f = (t & 31) * 4;
        #pragma unroll
        for (int it = 0; it < 8; ++it) {
            const int o = (t >> 5) + it * 8;
            float4 v = *(const float4*)&W[(size_t)(ohalf * 64 + o) * F_ + f];
            Wt[f][o] = v.x; Wt[f + 1][o] = v.y;
            Wt[f + 2][o] = v.z; Wt[f + 3][o] = v.w;
        }
    }
    {
        const int f = t & 127;
        const int which = t >> 7;
        const float* av = a + which * 128;
        float acc = 0.f;
        for (int o = 0; o < 128; ++o)
            acc += W[(size_t)o * F_ + f] * av[o];
        if (which == 0) wsm[f] = acc; else wtm[f] = acc;
    }
    __syncthreads();

    const int o4 = t & 15;
    const int r4 = t >> 4;
    float acc[4][4];
    #pragma unroll
    for (int i = 0; i < 4; ++i)
        #pragma unroll
        for (int j = 0; j < 4; ++j) acc[i][j] = 0.f;

    #pragma unroll 4
    for (int k = 0; k < 128; ++k) {
        float4 w = *(const float4*)&Wt[k][o4 * 4];
        float h0 = h_s[r4 * 4 + 0][k];
        float h1 = h_s[r4 * 4 + 1][k];
        float h2 = h_s[r4 * 4 + 2][k];
        float h3 = h_s[r4 * 4 + 3][k];
        acc[0][0] += h0 * w.x; acc[0][1] += h0 * w.y; acc[0][2] += h0 * w.z; acc[0][3] += h0 * w.w;
        acc[1][0] += h1 * w.x; acc[1][1] += h1 * w.y; acc[1][2] += h1 * w.z; acc[1][3] += h1 * w.w;
        acc[2][0] += h2 * w.x; acc[2][1] += h2 * w.y; acc[2][2] += h2 * w.z; acc[2][3] += h2 * w.w;
        acc[3][0] += h3 * w.x; acc[3][1] += h3 * w.y; acc[3][2] += h3 * w.z; acc[3][3] += h3 * w.w;
    }

    {
        const int Rbase = r0 + r4 * 4;
        const int b    = Rbase >> 11;
        const int jj   = Rbase & 2047;
        const int jblk = jj >> 5;
        const int k8   = (jj >> 3) & 3;
        const int kk   = jj & 7;
        #pragma unroll
        for (int jo = 0; jo < 4; ++jo) {
            const int o = ohalf * 64 + o4 * 4 + jo;
            size_t off = ((size_t)(b * 64 + jblk) * 128 + o) * 32 + k8 * 8 + kk;
            union { _Float16 x[4]; uint2 u; } pk;
            pk.x[0] = (_Float16)acc[0][jo];
            pk.x[1] = (_Float16)acc[1][jo];
            pk.x[2] = (_Float16)acc[2][jo];
            pk.x[3] = (_Float16)acc[3][jo];
            *(uint2*)(WhH + off) = pk.u;
        }
    }

    {
        const int r = t & 63, part = t >> 6;
        float as_ = 0.f, at_ = 0.f;
        const int kb = part * 32;
        for (int k = kb; k < kb + 32; ++k) {
            float hv = h_s[r][k];
            as_ += hv * wsm[k];
            at_ += hv * wtm[k];
        }
        sred[r][part] = as_; tred[r][part] = at_;
    }
    __syncthreads();
    if (ohalf == 0 && t < 64) {
        sv[r0 + t] = sred[t][0] + sred[t][1] + sred[t][2] + sred[t][3];
        tv[r0 + t] = tred[t][0] + tred[t][1] + tred[t][2] + tred[t][3];
    }
}

// ---------------------------------------------------------------------------
// Kernel 2: flash-GAT, barrier-free main loop.
// 1024 blocks x 256 threads; block = (b, 16-row i-tile); wave wv owns
// j in [wv*512, wv*512+512), 16 chunks of 32.
// Each lane computes its 8 P values directly in A-fragment register layout
// (row m_=lane&15, k = q_*8+kk) -- no LDS round trip, no barriers in loop.
// 8 MFMAs/chunk cover all 128 o's. End: 4-wave partial-O/l reduce via LDS.
// ---------------------------------------------------------------------------
__global__ __launch_bounds__(256, 4) void k_attn(
    const _Float16* __restrict__ WhH, const float* __restrict__ sv,
    const float* __restrict__ tv, const int* __restrict__ adj,
    float* __restrict__ out)
{
    __shared__ float redO[4][16][128];   // 32 KB
    __shared__ float redL[4][16];
    __shared__ float tmr[4];

    const int t  = threadIdx.x;
    const int b  = blockIdx.x >> 7;
    const int i0 = (blockIdx.x & 127) * 16;
    const float* tb = tv + ((size_t)b << 11);

    // per-batch tmax (8 KB, L2-hot)
    float tm = -INFINITY;
    #pragma unroll
    for (int k = 0; k < 8; ++k) tm = fmaxf(tm, tb[t + k * 256]);
    #pragma unroll
    for (int k = 32; k; k >>= 1) tm = fmaxf(tm, __shfl_xor(tm, k, 64));
    if ((t & 63) == 0) tmr[t >> 6] = tm;
    __syncthreads();
    const float tmax = fmaxf(fmaxf(tmr[0], tmr[1]), fmaxf(tmr[2], tmr[3]));

    const int wv   = t >> 6;
    const int lane = t & 63;
    const int m_   = lane & 15;
    const int q_   = lane >> 4;

    const float s_i = sv[((size_t)b << 11) + i0 + m_];
    const float M_i = fmaxf(s_i + tmax, 0.f);   // provable upper bound on e

    const int jbase = wv * 512;
    const int* arow = adj + ((size_t)(((b << 11) + i0 + m_)) << 11) + q_ * 8;
    const float* tq = tb + q_ * 8;
    const _Float16* wbase = WhH + (((size_t)b * 64) << 12)
                          + (size_t)m_ * 32 + q_ * 8;

    f32x4 acc[8];
    #pragma unroll
    for (int n = 0; n < 8; ++n) acc[n] = (f32x4){0.f, 0.f, 0.f, 0.f};
    float lsum = 0.f;

    int4 aL = *(const int4*)&arow[jbase];
    int4 aH = *(const int4*)&arow[jbase + 4];

    for (int jj = 0; jj < 16; ++jj) {
        const int j0 = jbase + jj * 32;
        const int jn = jbase + ((jj + 1) & 15) * 32;   // wrap: harmless
        int4 naL = *(const int4*)&arow[jn];
        int4 naH = *(const int4*)&arow[jn + 4];

        float4 tL = *(const float4*)&tq[j0];
        float4 tH = *(const float4*)&tq[j0 + 4];

        float e, p[8];
        e = s_i + tL.x; e = fmaxf(e, 0.2f * e); p[0] = aL.x ? __expf(e - M_i) : 0.f;
        e = s_i + tL.y; e = fmaxf(e, 0.2f * e); p[1] = aL.y ? __expf(e - M_i) : 0.f;
        e = s_i + tL.z; e = fmaxf(e, 0.2f * e); p[2] = aL.z ? __expf(e - M_i) : 0.f;
        e = s_i + tL.w; e = fmaxf(e, 0.2f * e); p[3] = aL.w ? __expf(e - M_i) : 0.f;
        e = s_i + tH.x; e = fmaxf(e, 0.2f * e); p[4] = aH.x ? __expf(e - M_i) : 0.f;
        e = s_i + tH.y; e = fmaxf(e, 0.2f * e); p[5] = aH.y ? __expf(e - M_i) : 0.f;
        e = s_i + tH.z; e = fmaxf(e, 0.2f * e); p[6] = aH.z ? __expf(e - M_i) : 0.f;
        e = s_i + tH.w; e = fmaxf(e, 0.2f * e); p[7] = aH.w ? __expf(e - M_i) : 0.f;

        lsum += ((p[0] + p[1]) + (p[2] + p[3])) + ((p[4] + p[5]) + (p[6] + p[7]));

        half8 af;
        #pragma unroll
        for (int k = 0; k < 8; ++k) af[k] = (_Float16)p[k];

        const _Float16* wb = wbase + ((size_t)(j0 >> 5) << 12);
        #pragma unroll
        for (int n = 0; n < 8; ++n) {
            half8 bf = *(const half8*)(wb + n * 512);
            acc[n] = __builtin_amdgcn_mfma_f32_16x16x32_f16(af, bf, acc[n], 0, 0, 0);
        }
        aL = naL; aH = naH;
    }

    // intra-wave l reduce over q-lanes (bits 4,5 of lane)
    lsum += __shfl_xor(lsum, 16, 64);
    lsum += __shfl_xor(lsum, 32, 64);
    if (q_ == 0) redL[wv][m_] = lsum;

    // dump partial O (C/D layout: row = q_*4+reg, col = n*16+m_)
    #pragma unroll
    for (int n = 0; n < 8; ++n)
        #pragma unroll
        for (int r = 0; r < 4; ++r)
            redO[wv][q_ * 4 + r][n * 16 + m_] = acc[n][r];
    __syncthreads();

    // combine 4 waves; thread t -> row t>>4, cols (t&15)*8..+8
    {
        const int row = t >> 4;
        const int c0  = (t & 15) * 8;
        const float li = redL[0][row] + redL[1][row] + redL[2][row] + redL[3][row];
        const float sc = li > 0.f ? 1.f / li : 0.f;   // empty row -> 0 (nan_to_num)
        float* op = out + (((size_t)((b << 11) + i0 + row)) << 7) + c0;
        #pragma unroll
        for (int c = 0; c < 8; ++c) {
            float v = redO[0][row][c0 + c] + redO[1][row][c0 + c]
                    + redO[2][row][c0 + c] + redO[3][row][c0 + c];
            op[c] = v * sc;
        }
    }
}

extern "C" void kernel_launch(void* const* d_in, const int* in_sizes, int n_in,
                              void* d_out, int out_size, void* d_ws, size_t ws_size,
                              hipStream_t stream) {
    const float* h   = (const float*)d_in[0];
    const int*   adj = (const int*)d_in[1];
    const float* W   = (const float*)d_in[2];
    const float* a   = (const float*)d_in[3];
    float* out = (float*)d_out;

    _Float16* WhH = (_Float16*)d_ws;                         // 4 MB
    float* sv = (float*)((char*)d_ws + (size_t)4 * 1024 * 1024);
    float* tv = sv + (size_t)B_ * N_;

    k_wh<<<512, 256, 0, stream>>>(h, W, a, WhH, sv, tv);
    k_attn<<<1024, 256, 0, stream>>>(WhH, sv, tv, adj, out);
}